// Round 1
// baseline (1284.896 us; speedup 1.0000x reference)
//
#include <hip/hip_runtime.h>

#define D 2048
#define M 512
#define STEPS 20
#define SPLITK 4
#define TS 64
#define KB 16
#define LDP 68   // padded LDS stride (keeps 16B alignment: 68*4=272=16*17)

// P[s] = X[s*512:(s+1)*512, :]^T @ X[s*512:(s+1)*512, :]
// grid (M/TS, M/TS, SPLITK), block 256
__global__ __launch_bounds__(256)
void gram_partial(const float* __restrict__ X, float* __restrict__ P) {
    __shared__ float As[KB][LDP];
    __shared__ float Bs[KB][LDP];
    const int ti = blockIdx.x * TS;
    const int tj = blockIdx.y * TS;
    const int k0base = blockIdx.z * (D / SPLITK);
    const int t  = threadIdx.x;
    const int tx = t & 15, ty = t >> 4;
    const int lrow = t >> 4;          // 0..15 (k within block)
    const int lcol = (t & 15) * 4;    // 0..60

    float acc[4][4] = {};

    for (int kb = 0; kb < (D / SPLITK); kb += KB) {
        const int krow = k0base + kb + lrow;
        const float4 a4 = *(const float4*)(X + (size_t)krow * M + ti + lcol);
        const float4 b4 = *(const float4*)(X + (size_t)krow * M + tj + lcol);
        *(float4*)(&As[lrow][lcol]) = a4;
        *(float4*)(&Bs[lrow][lcol]) = b4;
        __syncthreads();
        #pragma unroll
        for (int kk = 0; kk < KB; ++kk) {
            const float4 av = *(const float4*)(&As[kk][ty * 4]);
            const float4 bv = *(const float4*)(&Bs[kk][tx * 4]);
            const float a_[4] = {av.x, av.y, av.z, av.w};
            const float b_[4] = {bv.x, bv.y, bv.z, bv.w};
            #pragma unroll
            for (int i = 0; i < 4; ++i)
                #pragma unroll
                for (int j = 0; j < 4; ++j)
                    acc[i][j] = fmaf(a_[i], b_[j], acc[i][j]);
        }
        __syncthreads();
    }

    float* Pp = P + (size_t)blockIdx.z * M * M;
    #pragma unroll
    for (int i = 0; i < 4; ++i) {
        const int r = ti + ty * 4 + i;
        float4 v;
        v.x = acc[i][0]; v.y = acc[i][1]; v.z = acc[i][2]; v.w = acc[i][3];
        *(float4*)(Pp + (size_t)r * M + tj + tx * 4) = v;
    }
}

// A[i][j] = 1.5*(i==j) - 0.5 * sum_s P[s][i][j]
// grid 256, block 256 (each thread one float4)
__global__ __launch_bounds__(256)
void reduce_epilogue(const float* __restrict__ P, float* __restrict__ A) {
    const int idx = (blockIdx.x * 256 + threadIdx.x) * 4;
    float acc[4] = {};
    #pragma unroll
    for (int s = 0; s < SPLITK; ++s) {
        const float4 v = *(const float4*)(P + (size_t)s * M * M + idx);
        acc[0] += v.x; acc[1] += v.y; acc[2] += v.z; acc[3] += v.w;
    }
    const int i = idx >> 9;       // row
    const int j = idx & (M - 1);  // col of first elem
    float4 o;
    o.x = ((j + 0) == i ? 1.5f : 0.0f) - 0.5f * acc[0];
    o.y = ((j + 1) == i ? 1.5f : 0.0f) - 0.5f * acc[1];
    o.z = ((j + 2) == i ? 1.5f : 0.0f) - 0.5f * acc[2];
    o.w = ((j + 3) == i ? 1.5f : 0.0f) - 0.5f * acc[3];
    *(float4*)(A + idx) = o;
}

// Y = X @ A   (X: D x M row-major, A: M x M row-major)
// grid (D/TS, M/TS), block 256
__global__ __launch_bounds__(256)
void update(const float* __restrict__ X, const float* __restrict__ Amat,
            float* __restrict__ Y) {
    __shared__ float As[KB][LDP];  // As[k][i] = X[ti+i][k0+k]
    __shared__ float Bs[KB][LDP];  // Bs[k][j] = A[k0+k][tj+j]
    const int ti = blockIdx.x * TS;
    const int tj = blockIdx.y * TS;
    const int t  = threadIdx.x;
    const int tx = t & 15, ty = t >> 4;
    const int xr = t >> 2;          // 0..63 row of X tile
    const int xk = (t & 3) * 4;     // 0..12 k offset
    const int ar = t >> 4;          // 0..15 row of A tile
    const int ac = (t & 15) * 4;    // 0..60 col

    float acc[4][4] = {};

    for (int k0 = 0; k0 < M; k0 += KB) {
        const float4 xv = *(const float4*)(X + (size_t)(ti + xr) * M + k0 + xk);
        const float4 av = *(const float4*)(Amat + (size_t)(k0 + ar) * M + tj + ac);
        As[xk + 0][xr] = xv.x;
        As[xk + 1][xr] = xv.y;
        As[xk + 2][xr] = xv.z;
        As[xk + 3][xr] = xv.w;
        *(float4*)(&Bs[ar][ac]) = av;
        __syncthreads();
        #pragma unroll
        for (int kk = 0; kk < KB; ++kk) {
            const float4 av4 = *(const float4*)(&As[kk][ty * 4]);
            const float4 bv4 = *(const float4*)(&Bs[kk][tx * 4]);
            const float a_[4] = {av4.x, av4.y, av4.z, av4.w};
            const float b_[4] = {bv4.x, bv4.y, bv4.z, bv4.w};
            #pragma unroll
            for (int i = 0; i < 4; ++i)
                #pragma unroll
                for (int j = 0; j < 4; ++j)
                    acc[i][j] = fmaf(a_[i], b_[j], acc[i][j]);
        }
        __syncthreads();
    }

    #pragma unroll
    for (int i = 0; i < 4; ++i) {
        const int r = ti + ty * 4 + i;
        float4 v;
        v.x = acc[i][0]; v.y = acc[i][1]; v.z = acc[i][2]; v.w = acc[i][3];
        *(float4*)(Y + (size_t)r * M + tj + tx * 4) = v;
    }
}

extern "C" void kernel_launch(void* const* d_in, const int* in_sizes, int n_in,
                              void* d_out, int out_size, void* d_ws, size_t ws_size,
                              hipStream_t stream) {
    const float* Xin = (const float*)d_in[0];
    float* out = (float*)d_out;
    float* ws  = (float*)d_ws;

    float* Xbuf = ws;                    // D*M floats (4 MB)
    float* Amat = ws + (size_t)D * M;    // M*M floats (1 MB)
    float* P    = Amat + (size_t)M * M;  // SPLITK*M*M floats (4 MB)

    const dim3 ggrid(M / TS, M / TS, SPLITK);
    const dim3 ugrid(D / TS, M / TS);

    const float* cur = Xin;
    for (int it = 0; it < STEPS; ++it) {
        float* nxt = (it % 2 == 0) ? Xbuf : out;  // it=19 -> out
        gram_partial<<<ggrid, 256, 0, stream>>>(cur, P);
        reduce_epilogue<<<256, 256, 0, stream>>>(P, Amat);
        update<<<ugrid, 256, 0, stream>>>(cur, Amat, nxt);
        cur = nxt;
    }
}

// Round 2
// 633.308 us; speedup vs baseline: 2.0289x; 2.0289x over previous
//
#include <hip/hip_runtime.h>

#define D 2048
#define M 512
#define STEPS 20
#define GSPLIT 4
#define KB 32
#define LSTR 40   // LDS row stride in bf16 elems (80 B: 16B-aligned, 2-way banks = free)
#define CSTR 68   // epilogue fp32 LDS stride (272 B, 16B-aligned, odd dword-stride)

typedef __attribute__((ext_vector_type(8))) short bf16x8;
typedef __attribute__((ext_vector_type(4))) float f32x4;

__device__ inline unsigned short f2bf(float f) {
    union { float f; unsigned u; } v; v.f = f;
    unsigned r = v.u + 0x7fffu + ((v.u >> 16) & 1u);  // RNE
    return (unsigned short)(r >> 16);
}
__device__ inline float bf2f(unsigned short h) {
    union { float f; unsigned u; } v; v.u = ((unsigned)h) << 16;
    return v.f;
}
__device__ inline uint4 pack8(const unsigned short* h) {
    uint4 u;
    u.x = h[0] | ((unsigned)h[1] << 16);
    u.y = h[2] | ((unsigned)h[3] << 16);
    u.z = h[4] | ((unsigned)h[5] << 16);
    u.w = h[6] | ((unsigned)h[7] << 16);
    return u;
}
__device__ inline uint2 pack4(const unsigned short* h) {
    uint2 u;
    u.x = h[0] | ((unsigned)h[1] << 16);
    u.y = h[2] | ((unsigned)h[3] << 16);
    return u;
}

// X fp32 (D x M) -> hi/lo bf16 (D x M) and transposed hi/lo (M x D)
__global__ __launch_bounds__(256) void init_split(
    const float* __restrict__ X,
    unsigned short* __restrict__ Xhi, unsigned short* __restrict__ Xlo,
    unsigned short* __restrict__ XThi, unsigned short* __restrict__ XTlo) {
    const int t = blockIdx.x * 256 + threadIdx.x;
    const int base = t * 8;
    const int row = base >> 9;        // / M
    const int col = base & (M - 1);
    const float4 a = *(const float4*)(X + base);
    const float4 b = *(const float4*)(X + base + 4);
    const float v[8] = {a.x, a.y, a.z, a.w, b.x, b.y, b.z, b.w};
    unsigned short hi[8], lo[8];
    #pragma unroll
    for (int i = 0; i < 8; ++i) { hi[i] = f2bf(v[i]); lo[i] = f2bf(v[i] - bf2f(hi[i])); }
    *(uint4*)(Xhi + base) = pack8(hi);
    *(uint4*)(Xlo + base) = pack8(lo);
    #pragma unroll
    for (int i = 0; i < 8; ++i) {
        XThi[(size_t)(col + i) * D + row] = hi[i];
        XTlo[(size_t)(col + i) * D + row] = lo[i];
    }
}

// P[s] = partial X^T X over k-chunk s. Inputs: XT hi/lo (M x D, K-contiguous rows).
// grid (M/32, M/64, GSPLIT), block 256 (4 waves; wave w owns 16-col slice jj=w, 2 row-tiles)
__global__ __launch_bounds__(256) void gram_mfma(
    const unsigned short* __restrict__ XThi, const unsigned short* __restrict__ XTlo,
    float* __restrict__ P) {
    __shared__ __align__(16) char smem[(2 * 32 + 2 * 64) * LSTR * 2];  // 15360 B
    unsigned short* As = (unsigned short*)smem;         // [2][32][LSTR]
    unsigned short* Bs = As + 2 * 32 * LSTR;            // [2][64][LSTR]
    float* Ct = (float*)smem;                           // [32][CSTR] (reused epilogue)

    const int ti = blockIdx.x * 32;
    const int tj = blockIdx.y * 64;
    const int k0b = blockIdx.z * (D / GSPLIT);
    const int t = threadIdx.x;
    const int lane = t & 63;
    const int w = t >> 6;
    const int lm = lane & 15;
    const int lq = lane >> 4;

    // staging decode: As = 256 chunks of 16B (1/thread), Bs = 512 chunks (2/thread)
    const int abuf = t >> 7, aidx = t & 127, am = aidx >> 2, ac = (aidx & 3) * 8;
    const unsigned short* aSrc = (abuf ? XTlo : XThi) + (size_t)(ti + am) * D + ac;
    unsigned short* aDst = As + (abuf * 32 + am) * LSTR + ac;

    f32x4 acc0 = {0.f, 0.f, 0.f, 0.f}, acc1 = {0.f, 0.f, 0.f, 0.f};

    for (int kb = 0; kb < D / GSPLIT; kb += KB) {
        const int k0 = k0b + kb;
        *(uint4*)aDst = *(const uint4*)(aSrc + k0);
        #pragma unroll
        for (int r = 0; r < 2; ++r) {
            const int idx2 = t + 256 * r;
            const int bbuf = idx2 >> 8, bidx = idx2 & 255;
            const int bn = bidx >> 2, bc = (bidx & 3) * 8;
            const unsigned short* src =
                (bbuf ? XTlo : XThi) + (size_t)(tj + bn) * D + k0 + bc;
            *(uint4*)(Bs + (bbuf * 64 + bn) * LSTR + bc) = *(const uint4*)src;
        }
        __syncthreads();
        const bf16x8 bhi = *(const bf16x8*)(Bs + (w * 16 + lm) * LSTR + lq * 8);
        const bf16x8 blo = *(const bf16x8*)(Bs + (64 + w * 16 + lm) * LSTR + lq * 8);
        const bf16x8 ah0 = *(const bf16x8*)(As + (lm) * LSTR + lq * 8);
        const bf16x8 ah1 = *(const bf16x8*)(As + (16 + lm) * LSTR + lq * 8);
        const bf16x8 al0 = *(const bf16x8*)(As + (32 + lm) * LSTR + lq * 8);
        const bf16x8 al1 = *(const bf16x8*)(As + (48 + lm) * LSTR + lq * 8);
        acc0 = __builtin_amdgcn_mfma_f32_16x16x32_bf16(ah0, bhi, acc0, 0, 0, 0);
        acc1 = __builtin_amdgcn_mfma_f32_16x16x32_bf16(ah1, bhi, acc1, 0, 0, 0);
        acc0 = __builtin_amdgcn_mfma_f32_16x16x32_bf16(ah0, blo, acc0, 0, 0, 0);
        acc1 = __builtin_amdgcn_mfma_f32_16x16x32_bf16(ah1, blo, acc1, 0, 0, 0);
        acc0 = __builtin_amdgcn_mfma_f32_16x16x32_bf16(al0, bhi, acc0, 0, 0, 0);
        acc1 = __builtin_amdgcn_mfma_f32_16x16x32_bf16(al1, bhi, acc1, 0, 0, 0);
        __syncthreads();
    }

    // C-layout -> LDS -> wide stores
    #pragma unroll
    for (int r = 0; r < 4; ++r) {
        Ct[(lq * 4 + r) * CSTR + (w * 16 + lm)] = acc0[r];
        Ct[(16 + lq * 4 + r) * CSTR + (w * 16 + lm)] = acc1[r];
    }
    __syncthreads();
    const int rr = t >> 3, c0 = (t & 7) * 8;
    const float4 f0 = *(const float4*)(Ct + rr * CSTR + c0);
    const float4 f1 = *(const float4*)(Ct + rr * CSTR + c0 + 4);
    float* Pp = P + (size_t)blockIdx.z * M * M + (size_t)(ti + rr) * M + tj + c0;
    *(float4*)Pp = f0;
    *(float4*)(Pp + 4) = f1;
}

// A = 1.5 I - 0.5 * sum_s P[s], emitted as hi/lo bf16. grid 256 x 256 thr.
__global__ __launch_bounds__(256) void reduce_a(
    const float* __restrict__ P,
    unsigned short* __restrict__ Ahi, unsigned short* __restrict__ Alo) {
    const int idx = (blockIdx.x * 256 + threadIdx.x) * 4;
    float s[4] = {0.f, 0.f, 0.f, 0.f};
    #pragma unroll
    for (int sp = 0; sp < GSPLIT; ++sp) {
        const float4 v = *(const float4*)(P + (size_t)sp * M * M + idx);
        s[0] += v.x; s[1] += v.y; s[2] += v.z; s[3] += v.w;
    }
    const int i = idx >> 9, j = idx & (M - 1);
    unsigned short hi[4], lo[4];
    #pragma unroll
    for (int c = 0; c < 4; ++c) {
        const float a = ((j + c) == i ? 1.5f : 0.0f) - 0.5f * s[c];
        hi[c] = f2bf(a); lo[c] = f2bf(a - bf2f(hi[c]));
    }
    *(uint2*)(Ahi + idx) = pack4(hi);
    *(uint2*)(Alo + idx) = pack4(lo);
}

// Y = X @ A (A symmetric, read as rows). Writes Y hi/lo + YT hi/lo, or fp32 out on last.
// grid (D/32, M/64), block 256.
__global__ __launch_bounds__(256) void update_mfma(
    const unsigned short* __restrict__ Xhi, const unsigned short* __restrict__ Xlo,
    const unsigned short* __restrict__ Ahi, const unsigned short* __restrict__ Alo,
    unsigned short* __restrict__ Yhi, unsigned short* __restrict__ Ylo,
    unsigned short* __restrict__ YThi, unsigned short* __restrict__ YTlo,
    float* __restrict__ Yout, const int last) {
    __shared__ __align__(16) char smem[(2 * 32 + 2 * 64) * LSTR * 2];
    unsigned short* As = (unsigned short*)smem;
    unsigned short* Bs = As + 2 * 32 * LSTR;
    float* Ct = (float*)smem;

    const int ti = blockIdx.x * 32;   // Y rows
    const int tj = blockIdx.y * 64;   // Y cols
    const int t = threadIdx.x;
    const int lane = t & 63;
    const int w = t >> 6;
    const int lm = lane & 15;
    const int lq = lane >> 4;

    const int abuf = t >> 7, aidx = t & 127, am = aidx >> 2, ac = (aidx & 3) * 8;
    const unsigned short* aSrc = (abuf ? Xlo : Xhi) + (size_t)(ti + am) * M + ac;
    unsigned short* aDst = As + (abuf * 32 + am) * LSTR + ac;

    f32x4 acc0 = {0.f, 0.f, 0.f, 0.f}, acc1 = {0.f, 0.f, 0.f, 0.f};

    for (int k0 = 0; k0 < M; k0 += KB) {
        *(uint4*)aDst = *(const uint4*)(aSrc + k0);
        #pragma unroll
        for (int r = 0; r < 2; ++r) {
            const int idx2 = t + 256 * r;
            const int bbuf = idx2 >> 8, bidx = idx2 & 255;
            const int bn = bidx >> 2, bc = (bidx & 3) * 8;
            const unsigned short* src =
                (bbuf ? Alo : Ahi) + (size_t)(tj + bn) * M + k0 + bc;
            *(uint4*)(Bs + (bbuf * 64 + bn) * LSTR + bc) = *(const uint4*)src;
        }
        __syncthreads();
        const bf16x8 bhi = *(const bf16x8*)(Bs + (w * 16 + lm) * LSTR + lq * 8);
        const bf16x8 blo = *(const bf16x8*)(Bs + (64 + w * 16 + lm) * LSTR + lq * 8);
        const bf16x8 ah0 = *(const bf16x8*)(As + (lm) * LSTR + lq * 8);
        const bf16x8 ah1 = *(const bf16x8*)(As + (16 + lm) * LSTR + lq * 8);
        const bf16x8 al0 = *(const bf16x8*)(As + (32 + lm) * LSTR + lq * 8);
        const bf16x8 al1 = *(const bf16x8*)(As + (48 + lm) * LSTR + lq * 8);
        acc0 = __builtin_amdgcn_mfma_f32_16x16x32_bf16(ah0, bhi, acc0, 0, 0, 0);
        acc1 = __builtin_amdgcn_mfma_f32_16x16x32_bf16(ah1, bhi, acc1, 0, 0, 0);
        acc0 = __builtin_amdgcn_mfma_f32_16x16x32_bf16(ah0, blo, acc0, 0, 0, 0);
        acc1 = __builtin_amdgcn_mfma_f32_16x16x32_bf16(ah1, blo, acc1, 0, 0, 0);
        acc0 = __builtin_amdgcn_mfma_f32_16x16x32_bf16(al0, bhi, acc0, 0, 0, 0);
        acc1 = __builtin_amdgcn_mfma_f32_16x16x32_bf16(al1, bhi, acc1, 0, 0, 0);
        __syncthreads();
    }

    #pragma unroll
    for (int r = 0; r < 4; ++r) {
        Ct[(lq * 4 + r) * CSTR + (w * 16 + lm)] = acc0[r];
        Ct[(16 + lq * 4 + r) * CSTR + (w * 16 + lm)] = acc1[r];
    }
    __syncthreads();
    const int rr = t >> 3, c0 = (t & 7) * 8;
    const float4 f0 = *(const float4*)(Ct + rr * CSTR + c0);
    const float4 f1 = *(const float4*)(Ct + rr * CSTR + c0 + 4);
    if (last) {
        float* o = Yout + (size_t)(ti + rr) * M + tj + c0;
        *(float4*)o = f0;
        *(float4*)(o + 4) = f1;
    } else {
        const float v[8] = {f0.x, f0.y, f0.z, f0.w, f1.x, f1.y, f1.z, f1.w};
        unsigned short hi[8], lo[8];
        #pragma unroll
        for (int i = 0; i < 8; ++i) { hi[i] = f2bf(v[i]); lo[i] = f2bf(v[i] - bf2f(hi[i])); }
        *(uint4*)(Yhi + (size_t)(ti + rr) * M + tj + c0) = pack8(hi);
        *(uint4*)(Ylo + (size_t)(ti + rr) * M + tj + c0) = pack8(lo);
        // transposed copy for the next gram
        const int c = t & 63, r0 = (t >> 6) * 8;
        float u[8];
        #pragma unroll
        for (int i = 0; i < 8; ++i) u[i] = Ct[(r0 + i) * CSTR + c];
        unsigned short thi[8], tlo[8];
        #pragma unroll
        for (int i = 0; i < 8; ++i) { thi[i] = f2bf(u[i]); tlo[i] = f2bf(u[i] - bf2f(thi[i])); }
        *(uint4*)(YThi + (size_t)(tj + c) * D + ti + r0) = pack8(thi);
        *(uint4*)(YTlo + (size_t)(tj + c) * D + ti + r0) = pack8(tlo);
    }
}

extern "C" void kernel_launch(void* const* d_in, const int* in_sizes, int n_in,
                              void* d_out, int out_size, void* d_ws, size_t ws_size,
                              hipStream_t stream) {
    const float* Xin = (const float*)d_in[0];
    float* out = (float*)d_out;
    char* w = (char*)d_ws;
    const size_t XB = (size_t)D * M * 2;  // 2 MB per bf16 D x M buffer

    unsigned short* Xhi[2] = {(unsigned short*)(w), (unsigned short*)(w + XB)};
    unsigned short* Xlo[2] = {(unsigned short*)(w + 2 * XB), (unsigned short*)(w + 3 * XB)};
    unsigned short* XThi = (unsigned short*)(w + 4 * XB);
    unsigned short* XTlo = (unsigned short*)(w + 5 * XB);
    unsigned short* Ahi = (unsigned short*)(w + 6 * XB);
    unsigned short* Alo = Ahi + (size_t)M * M;
    float* P = out;  // overlay split-K partials on d_out (4 MB), overwritten by last update

    init_split<<<D * M / 2048, 256, 0, stream>>>(Xin, Xhi[0], Xlo[0], XThi, XTlo);

    for (int it = 0; it < STEPS; ++it) {
        const int cur = it & 1, nxt = cur ^ 1;
        const int last = (it == STEPS - 1);
        gram_mfma<<<dim3(M / 32, M / 64, GSPLIT), 256, 0, stream>>>(XThi, XTlo, P);
        reduce_a<<<M * M / 1024, 256, 0, stream>>>(P, Ahi, Alo);
        update_mfma<<<dim3(D / 32, M / 64), 256, 0, stream>>>(
            Xhi[cur], Xlo[cur], Ahi, Alo,
            Xhi[nxt], Xlo[nxt], XThi, XTlo, out, last);
    }
}

// Round 3
// 411.699 us; speedup vs baseline: 3.1210x; 1.5383x over previous
//
#include <hip/hip_runtime.h>

#define D 2048
#define M 512
#define STEPS 10
#define KB 32
#define LSTR 40   // LDS stage row stride in bf16 elems (80 B)
#define CSTR 68   // update epilogue fp32 stride
#define GSTR 36   // gram epilogue fp32 stride

typedef __attribute__((ext_vector_type(8))) short bf16x8;
typedef __attribute__((ext_vector_type(4))) float f32x4;

__device__ inline unsigned short f2bf(float f) {
    union { float f; unsigned u; } v; v.f = f;
    unsigned r = v.u + 0x7fffu + ((v.u >> 16) & 1u);  // RNE
    return (unsigned short)(r >> 16);
}
__device__ inline float bf2f(unsigned short h) {
    union { float f; unsigned u; } v; v.u = ((unsigned)h) << 16;
    return v.f;
}
__device__ inline uint4 pack8(const unsigned short* h) {
    uint4 u;
    u.x = h[0] | ((unsigned)h[1] << 16);
    u.y = h[2] | ((unsigned)h[3] << 16);
    u.z = h[4] | ((unsigned)h[5] << 16);
    u.w = h[6] | ((unsigned)h[7] << 16);
    return u;
}
__device__ inline uint2 pack4(const unsigned short* h) {
    uint2 u;
    u.x = h[0] | ((unsigned)h[1] << 16);
    u.y = h[2] | ((unsigned)h[3] << 16);
    return u;
}

// X fp32 (D x M) -> hi/lo bf16 (D x M) and transposed hi/lo (M x D)
__global__ __launch_bounds__(256) void init_split(
    const float* __restrict__ X,
    unsigned short* __restrict__ Xhi, unsigned short* __restrict__ Xlo,
    unsigned short* __restrict__ XThi, unsigned short* __restrict__ XTlo) {
    const int t = blockIdx.x * 256 + threadIdx.x;
    const int base = t * 8;
    const int row = base >> 9;
    const int col = base & (M - 1);
    const float4 a = *(const float4*)(X + base);
    const float4 b = *(const float4*)(X + base + 4);
    const float v[8] = {a.x, a.y, a.z, a.w, b.x, b.y, b.z, b.w};
    unsigned short hi[8], lo[8];
    #pragma unroll
    for (int i = 0; i < 8; ++i) { hi[i] = f2bf(v[i]); lo[i] = f2bf(v[i] - bf2f(hi[i])); }
    *(uint4*)(Xhi + base) = pack8(hi);
    *(uint4*)(Xlo + base) = pack8(lo);
    #pragma unroll
    for (int i = 0; i < 8; ++i) {
        XThi[(size_t)(col + i) * D + row] = hi[i];
        XTlo[(size_t)(col + i) * D + row] = lo[i];
    }
}

// A = 1.5 I - 0.5 X^T X, emitted hi/lo bf16. grid (16,16), block 256 (2x2 waves).
// Double-buffered LDS, register prefetch, one barrier per K-iter.
__global__ __launch_bounds__(256) void gram_a(
    const unsigned short* __restrict__ XThi, const unsigned short* __restrict__ XTlo,
    unsigned short* __restrict__ Ahi, unsigned short* __restrict__ Alo) {
    __shared__ __align__(16) unsigned short sm[2 * 128 * LSTR];  // 20480 B
    const int ti = blockIdx.x * 32;
    const int tj = blockIdx.y * 32;
    const int t = threadIdx.x;
    const int lane = t & 63;
    const int w = t >> 6;
    const int wi = w & 1, wj = w >> 1;
    const int lm = lane & 15, lq = lane >> 4;

    // staging: 512 chunks of 16B, 2 per thread
    // lrow 0-31: A-hi, 32-63: A-lo, 64-95: B-hi, 96-127: B-lo
    const unsigned short* src[2];
    int dstoff[2];
    #pragma unroll
    for (int r = 0; r < 2; ++r) {
        const int c = t + 256 * r;
        const int lrow = c >> 2;
        const int lcol = (c & 3) * 8;
        const int side = lrow >> 6;
        const int buf = (lrow >> 5) & 1;
        const int m = lrow & 31;
        src[r] = (buf ? XTlo : XThi) + (size_t)((side ? tj : ti) + m) * D + lcol;
        dstoff[r] = lrow * LSTR + lcol;
    }

    f32x4 a1 = {0.f, 0.f, 0.f, 0.f}, a2 = {0.f, 0.f, 0.f, 0.f};
    uint4 p0 = *(const uint4*)(src[0]);
    uint4 p1 = *(const uint4*)(src[1]);
    int cur = 0;

    for (int k0 = 0; k0 < D; k0 += KB) {
        unsigned short* S = sm + cur * (128 * LSTR);
        *(uint4*)(S + dstoff[0]) = p0;
        *(uint4*)(S + dstoff[1]) = p1;
        __syncthreads();
        if (k0 + KB < D) {
            p0 = *(const uint4*)(src[0] + k0 + KB);
            p1 = *(const uint4*)(src[1] + k0 + KB);
        }
        const bf16x8 ah = *(const bf16x8*)(S + (wi * 16 + lm) * LSTR + lq * 8);
        const bf16x8 al = *(const bf16x8*)(S + (32 + wi * 16 + lm) * LSTR + lq * 8);
        const bf16x8 bh = *(const bf16x8*)(S + (64 + wj * 16 + lm) * LSTR + lq * 8);
        const bf16x8 bl = *(const bf16x8*)(S + (96 + wj * 16 + lm) * LSTR + lq * 8);
        a1 = __builtin_amdgcn_mfma_f32_16x16x32_bf16(ah, bh, a1, 0, 0, 0);
        a2 = __builtin_amdgcn_mfma_f32_16x16x32_bf16(ah, bl, a2, 0, 0, 0);
        a2 = __builtin_amdgcn_mfma_f32_16x16x32_bf16(al, bh, a2, 0, 0, 0);
        cur ^= 1;
    }

    const f32x4 g = a1 + a2;
    __syncthreads();
    float* Ct = (float*)sm;
    #pragma unroll
    for (int r = 0; r < 4; ++r)
        Ct[(wi * 16 + lq * 4 + r) * GSTR + (wj * 16 + lm)] = g[r];
    __syncthreads();
    const int rr = t >> 3, c0 = (t & 7) * 4;
    const float4 gv = *(const float4*)(Ct + rr * GSTR + c0);
    const int row = ti + rr;
    const float gg[4] = {gv.x, gv.y, gv.z, gv.w};
    unsigned short hi[4], lo[4];
    #pragma unroll
    for (int c = 0; c < 4; ++c) {
        const float a = ((tj + c0 + c) == row ? 1.5f : 0.0f) - 0.5f * gg[c];
        hi[c] = f2bf(a); lo[c] = f2bf(a - bf2f(hi[c]));
    }
    *(uint2*)(Ahi + (size_t)row * M + tj + c0) = pack4(hi);
    *(uint2*)(Alo + (size_t)row * M + tj + c0) = pack4(lo);
}

// Y = X @ A (A symmetric). grid (D/32, M/64), block 256. Double-buffered.
__global__ __launch_bounds__(256) void update_mfma(
    const unsigned short* __restrict__ Xhi, const unsigned short* __restrict__ Xlo,
    const unsigned short* __restrict__ Ahi, const unsigned short* __restrict__ Alo,
    unsigned short* __restrict__ Yhi, unsigned short* __restrict__ Ylo,
    unsigned short* __restrict__ YThi, unsigned short* __restrict__ YTlo,
    float* __restrict__ Yout, const int last) {
    __shared__ __align__(16) unsigned short sm[2 * 192 * LSTR];  // 30720 B
    const int ti = blockIdx.x * 32;
    const int tj = blockIdx.y * 64;
    const int t = threadIdx.x;
    const int lane = t & 63;
    const int w = t >> 6;
    const int lm = lane & 15, lq = lane >> 4;

    // staging: 768 chunks, 3/thread.
    // rows 0-31 X-hi, 32-63 X-lo, 64-127 A-hi, 128-191 A-lo
    const unsigned short* src[3];
    int dstoff[3];
    #pragma unroll
    for (int r = 0; r < 3; ++r) {
        const int c = t + 256 * r;
        if (c < 256) {
            const int buf = c >> 7;
            const int am = (c >> 2) & 31;
            const int ac = (c & 3) * 8;
            src[r] = (buf ? Xlo : Xhi) + (size_t)(ti + am) * M + ac;
            dstoff[r] = (buf * 32 + am) * LSTR + ac;
        } else {
            const int b = c - 256;
            const int buf = b >> 8;
            const int bn = (b >> 2) & 63;
            const int bc = (b & 3) * 8;
            src[r] = (buf ? Alo : Ahi) + (size_t)(tj + bn) * M + bc;
            dstoff[r] = (64 + buf * 64 + bn) * LSTR + bc;
        }
    }

    f32x4 h0 = {0.f,0.f,0.f,0.f}, c0a = {0.f,0.f,0.f,0.f};
    f32x4 h1 = {0.f,0.f,0.f,0.f}, c1a = {0.f,0.f,0.f,0.f};
    uint4 p0 = *(const uint4*)(src[0]);
    uint4 p1 = *(const uint4*)(src[1]);
    uint4 p2 = *(const uint4*)(src[2]);
    int cur = 0;

    for (int k0 = 0; k0 < M; k0 += KB) {
        unsigned short* S = sm + cur * (192 * LSTR);
        *(uint4*)(S + dstoff[0]) = p0;
        *(uint4*)(S + dstoff[1]) = p1;
        *(uint4*)(S + dstoff[2]) = p2;
        __syncthreads();
        if (k0 + KB < M) {
            p0 = *(const uint4*)(src[0] + k0 + KB);
            p1 = *(const uint4*)(src[1] + k0 + KB);
            p2 = *(const uint4*)(src[2] + k0 + KB);
        }
        const bf16x8 ah0 = *(const bf16x8*)(S + (lm) * LSTR + lq * 8);
        const bf16x8 ah1 = *(const bf16x8*)(S + (16 + lm) * LSTR + lq * 8);
        const bf16x8 al0 = *(const bf16x8*)(S + (32 + lm) * LSTR + lq * 8);
        const bf16x8 al1 = *(const bf16x8*)(S + (48 + lm) * LSTR + lq * 8);
        const bf16x8 bh  = *(const bf16x8*)(S + (64 + w * 16 + lm) * LSTR + lq * 8);
        const bf16x8 bl  = *(const bf16x8*)(S + (128 + w * 16 + lm) * LSTR + lq * 8);
        h0  = __builtin_amdgcn_mfma_f32_16x16x32_bf16(ah0, bh, h0, 0, 0, 0);
        c0a = __builtin_amdgcn_mfma_f32_16x16x32_bf16(ah0, bl, c0a, 0, 0, 0);
        c0a = __builtin_amdgcn_mfma_f32_16x16x32_bf16(al0, bh, c0a, 0, 0, 0);
        h1  = __builtin_amdgcn_mfma_f32_16x16x32_bf16(ah1, bh, h1, 0, 0, 0);
        c1a = __builtin_amdgcn_mfma_f32_16x16x32_bf16(ah1, bl, c1a, 0, 0, 0);
        c1a = __builtin_amdgcn_mfma_f32_16x16x32_bf16(al1, bh, c1a, 0, 0, 0);
        cur ^= 1;
    }

    const f32x4 acc0 = h0 + c0a;
    const f32x4 acc1 = h1 + c1a;
    __syncthreads();
    float* Ct = (float*)sm;
    #pragma unroll
    for (int r = 0; r < 4; ++r) {
        Ct[(lq * 4 + r) * CSTR + (w * 16 + lm)] = acc0[r];
        Ct[(16 + lq * 4 + r) * CSTR + (w * 16 + lm)] = acc1[r];
    }
    __syncthreads();
    const int rr = t >> 3, cc = (t & 7) * 8;
    const float4 f0 = *(const float4*)(Ct + rr * CSTR + cc);
    const float4 f1 = *(const float4*)(Ct + rr * CSTR + cc + 4);
    if (last) {
        float* o = Yout + (size_t)(ti + rr) * M + tj + cc;
        *(float4*)o = f0;
        *(float4*)(o + 4) = f1;
    } else {
        const float v[8] = {f0.x, f0.y, f0.z, f0.w, f1.x, f1.y, f1.z, f1.w};
        unsigned short hi[8], lo[8];
        #pragma unroll
        for (int i = 0; i < 8; ++i) { hi[i] = f2bf(v[i]); lo[i] = f2bf(v[i] - bf2f(hi[i])); }
        *(uint4*)(Yhi + (size_t)(ti + rr) * M + tj + cc) = pack8(hi);
        *(uint4*)(Ylo + (size_t)(ti + rr) * M + tj + cc) = pack8(lo);
        const int c = t & 63, r0 = (t >> 6) * 8;
        float u[8];
        #pragma unroll
        for (int i = 0; i < 8; ++i) u[i] = Ct[(r0 + i) * CSTR + c];
        unsigned short thi[8], tlo[8];
        #pragma unroll
        for (int i = 0; i < 8; ++i) { thi[i] = f2bf(u[i]); tlo[i] = f2bf(u[i] - bf2f(thi[i])); }
        *(uint4*)(YThi + (size_t)(tj + c) * D + ti + r0) = pack8(thi);
        *(uint4*)(YTlo + (size_t)(tj + c) * D + ti + r0) = pack8(tlo);
    }
}

extern "C" void kernel_launch(void* const* d_in, const int* in_sizes, int n_in,
                              void* d_out, int out_size, void* d_ws, size_t ws_size,
                              hipStream_t stream) {
    const float* Xin = (const float*)d_in[0];
    float* out = (float*)d_out;
    char* w = (char*)d_ws;
    const size_t XB = (size_t)D * M * 2;  // 2 MB per bf16 D x M buffer

    unsigned short* Xhi[2] = {(unsigned short*)(w), (unsigned short*)(w + XB)};
    unsigned short* Xlo[2] = {(unsigned short*)(w + 2 * XB), (unsigned short*)(w + 3 * XB)};
    unsigned short* XThi = (unsigned short*)(w + 4 * XB);
    unsigned short* XTlo = (unsigned short*)(w + 5 * XB);
    unsigned short* Ahi = (unsigned short*)(w + 6 * XB);
    unsigned short* Alo = Ahi + (size_t)M * M;

    init_split<<<D * M / 2048, 256, 0, stream>>>(Xin, Xhi[0], Xlo[0], XThi, XTlo);

    for (int it = 0; it < STEPS; ++it) {
        const int cur = it & 1, nxt = cur ^ 1;
        const int last = (it == STEPS - 1);
        gram_a<<<dim3(M / 32, M / 32), 256, 0, stream>>>(XThi, XTlo, Ahi, Alo);
        update_mfma<<<dim3(D / 32, M / 64), 256, 0, stream>>>(
            Xhi[cur], Xlo[cur], Ahi, Alo,
            Xhi[nxt], Xlo[nxt], XThi, XTlo, out, last);
    }
}

// Round 4
// 292.460 us; speedup vs baseline: 4.3934x; 1.4077x over previous
//
#include <hip/hip_runtime.h>

#define D 2048
#define M 512
#define STEPS 8
#define GSPLIT 4
#define KB 32
#define LSTR 40   // LDS stage row stride in bf16 elems (80 B)
#define GSTR 36   // epilogue fp32 stride (32x32 tiles)

typedef __attribute__((ext_vector_type(8))) short bf16x8;
typedef __attribute__((ext_vector_type(4))) float f32x4;

__device__ inline unsigned short f2bf(float f) {
    union { float f; unsigned u; } v; v.f = f;
    unsigned r = v.u + 0x7fffu + ((v.u >> 16) & 1u);  // RNE
    return (unsigned short)(r >> 16);
}
__device__ inline float bf2f(unsigned short h) {
    union { float f; unsigned u; } v; v.u = ((unsigned)h) << 16;
    return v.f;
}
__device__ inline uint2 pack4(const unsigned short* h) {
    uint2 u;
    u.x = h[0] | ((unsigned)h[1] << 16);
    u.y = h[2] | ((unsigned)h[3] << 16);
    return u;
}
__device__ inline uint4 pack8(const unsigned short* h) {
    uint4 u;
    u.x = h[0] | ((unsigned)h[1] << 16);
    u.y = h[2] | ((unsigned)h[3] << 16);
    u.z = h[4] | ((unsigned)h[5] << 16);
    u.w = h[6] | ((unsigned)h[7] << 16);
    return u;
}

// X fp32 (D x M) -> hi/lo bf16 (D x M) and transposed hi/lo (M x D)
__global__ __launch_bounds__(256) void init_split(
    const float* __restrict__ X,
    unsigned short* __restrict__ Xhi, unsigned short* __restrict__ Xlo,
    unsigned short* __restrict__ XThi, unsigned short* __restrict__ XTlo) {
    const int t = blockIdx.x * 256 + threadIdx.x;
    const int base = t * 8;
    const int row = base >> 9;
    const int col = base & (M - 1);
    const float4 a = *(const float4*)(X + base);
    const float4 b = *(const float4*)(X + base + 4);
    const float v[8] = {a.x, a.y, a.z, a.w, b.x, b.y, b.z, b.w};
    unsigned short hi[8], lo[8];
    #pragma unroll
    for (int i = 0; i < 8; ++i) { hi[i] = f2bf(v[i]); lo[i] = f2bf(v[i] - bf2f(hi[i])); }
    *(uint4*)(Xhi + base) = pack8(hi);
    *(uint4*)(Xlo + base) = pack8(lo);
    #pragma unroll
    for (int i = 0; i < 8; ++i) {
        XThi[(size_t)(col + i) * D + row] = hi[i];
        XTlo[(size_t)(col + i) * D + row] = lo[i];
    }
}

// P[z] = partial X^T X over K-chunk z. grid (16,16,4), block 256 (2x2 waves).
// Double-buffered LDS, register prefetch, one barrier/iter, direct P stores.
__global__ __launch_bounds__(256) void gram_partial(
    const unsigned short* __restrict__ XThi, const unsigned short* __restrict__ XTlo,
    float* __restrict__ P) {
    __shared__ __align__(16) unsigned short sm[2 * 128 * LSTR];  // 20480 B
    const int ti = blockIdx.x * 32;
    const int tj = blockIdx.y * 32;
    const int k0b = blockIdx.z * (D / GSPLIT);
    const int t = threadIdx.x;
    const int lane = t & 63;
    const int w = t >> 6;
    const int wi = w & 1, wj = w >> 1;
    const int lm = lane & 15, lq = lane >> 4;

    // staging: 512 chunks of 16B, 2/thread. rows 0-31 A-hi, 32-63 A-lo, 64-95 B-hi, 96-127 B-lo
    const unsigned short* src[2];
    int dstoff[2];
    #pragma unroll
    for (int r = 0; r < 2; ++r) {
        const int c = t + 256 * r;
        const int lrow = c >> 2;
        const int lcol = (c & 3) * 8;
        const int side = lrow >> 6;
        const int buf = (lrow >> 5) & 1;
        const int m = lrow & 31;
        src[r] = (buf ? XTlo : XThi) + (size_t)((side ? tj : ti) + m) * D + k0b + lcol;
        dstoff[r] = lrow * LSTR + lcol;
    }

    f32x4 a1 = {0.f, 0.f, 0.f, 0.f}, a2 = {0.f, 0.f, 0.f, 0.f};
    uint4 p0 = *(const uint4*)(src[0]);
    uint4 p1 = *(const uint4*)(src[1]);
    int cur = 0;

    for (int kb = 0; kb < D / GSPLIT; kb += KB) {
        unsigned short* S = sm + cur * (128 * LSTR);
        *(uint4*)(S + dstoff[0]) = p0;
        *(uint4*)(S + dstoff[1]) = p1;
        __syncthreads();
        if (kb + KB < D / GSPLIT) {
            p0 = *(const uint4*)(src[0] + kb + KB);
            p1 = *(const uint4*)(src[1] + kb + KB);
        }
        const bf16x8 ah = *(const bf16x8*)(S + (wi * 16 + lm) * LSTR + lq * 8);
        const bf16x8 al = *(const bf16x8*)(S + (32 + wi * 16 + lm) * LSTR + lq * 8);
        const bf16x8 bh = *(const bf16x8*)(S + (64 + wj * 16 + lm) * LSTR + lq * 8);
        const bf16x8 bl = *(const bf16x8*)(S + (96 + wj * 16 + lm) * LSTR + lq * 8);
        a1 = __builtin_amdgcn_mfma_f32_16x16x32_bf16(ah, bh, a1, 0, 0, 0);
        a2 = __builtin_amdgcn_mfma_f32_16x16x32_bf16(ah, bl, a2, 0, 0, 0);
        a2 = __builtin_amdgcn_mfma_f32_16x16x32_bf16(al, bh, a2, 0, 0, 0);
        cur ^= 1;
    }

    const f32x4 g = a1 + a2;
    float* Pp = P + (size_t)blockIdx.z * M * M
              + (size_t)(ti + wi * 16 + lq * 4) * M + tj + wj * 16 + lm;
    #pragma unroll
    for (int r = 0; r < 4; ++r) Pp[(size_t)r * M] = g[r];
}

// A = 1.5 I - 0.5 * sum_z P[z], emitted hi/lo bf16. grid 256, block 256.
__global__ __launch_bounds__(256) void reduce_a(
    const float* __restrict__ P,
    unsigned short* __restrict__ Ahi, unsigned short* __restrict__ Alo) {
    const int idx = (blockIdx.x * 256 + threadIdx.x) * 4;
    float s[4] = {0.f, 0.f, 0.f, 0.f};
    #pragma unroll
    for (int sp = 0; sp < GSPLIT; ++sp) {
        const float4 v = *(const float4*)(P + (size_t)sp * M * M + idx);
        s[0] += v.x; s[1] += v.y; s[2] += v.z; s[3] += v.w;
    }
    const int i = idx >> 9, j = idx & (M - 1);
    unsigned short hi[4], lo[4];
    #pragma unroll
    for (int c = 0; c < 4; ++c) {
        const float a = ((j + c) == i ? 1.5f : 0.0f) - 0.5f * s[c];
        hi[c] = f2bf(a); lo[c] = f2bf(a - bf2f(hi[c]));
    }
    *(uint2*)(Ahi + idx) = pack4(hi);
    *(uint2*)(Alo + idx) = pack4(lo);
}

// Y = X @ A (A symmetric, rows as B-operand). grid (64,16), block 256 (2x2 waves).
__global__ __launch_bounds__(256) void update_mfma(
    const unsigned short* __restrict__ Xhi, const unsigned short* __restrict__ Xlo,
    const unsigned short* __restrict__ Ahi, const unsigned short* __restrict__ Alo,
    unsigned short* __restrict__ Yhi, unsigned short* __restrict__ Ylo,
    unsigned short* __restrict__ YThi, unsigned short* __restrict__ YTlo,
    float* __restrict__ Yout, const int last) {
    __shared__ __align__(16) unsigned short sm[2 * 128 * LSTR];  // 20480 B
    const int ti = blockIdx.x * 32;
    const int tj = blockIdx.y * 32;
    const int t = threadIdx.x;
    const int lane = t & 63;
    const int w = t >> 6;
    const int wi = w & 1, wj = w >> 1;
    const int lm = lane & 15, lq = lane >> 4;

    // staging: rows 0-31 X-hi, 32-63 X-lo, 64-95 A-hi, 96-127 A-lo
    const unsigned short* src[2];
    int dstoff[2];
    #pragma unroll
    for (int r = 0; r < 2; ++r) {
        const int c = t + 256 * r;
        const int lrow = c >> 2;
        const int lcol = (c & 3) * 8;
        const int side = lrow >> 6;
        const int buf = (lrow >> 5) & 1;
        const int m = lrow & 31;
        src[r] = side ? ((buf ? Alo : Ahi) + (size_t)(tj + m) * M + lcol)
                      : ((buf ? Xlo : Xhi) + (size_t)(ti + m) * M + lcol);
        dstoff[r] = lrow * LSTR + lcol;
    }

    f32x4 a1 = {0.f, 0.f, 0.f, 0.f}, a2 = {0.f, 0.f, 0.f, 0.f};
    uint4 p0 = *(const uint4*)(src[0]);
    uint4 p1 = *(const uint4*)(src[1]);
    int cur = 0;

    for (int k0 = 0; k0 < M; k0 += KB) {
        unsigned short* S = sm + cur * (128 * LSTR);
        *(uint4*)(S + dstoff[0]) = p0;
        *(uint4*)(S + dstoff[1]) = p1;
        __syncthreads();
        if (k0 + KB < M) {
            p0 = *(const uint4*)(src[0] + k0 + KB);
            p1 = *(const uint4*)(src[1] + k0 + KB);
        }
        const bf16x8 ah = *(const bf16x8*)(S + (wi * 16 + lm) * LSTR + lq * 8);
        const bf16x8 al = *(const bf16x8*)(S + (32 + wi * 16 + lm) * LSTR + lq * 8);
        const bf16x8 bh = *(const bf16x8*)(S + (64 + wj * 16 + lm) * LSTR + lq * 8);
        const bf16x8 bl = *(const bf16x8*)(S + (96 + wj * 16 + lm) * LSTR + lq * 8);
        a1 = __builtin_amdgcn_mfma_f32_16x16x32_bf16(ah, bh, a1, 0, 0, 0);
        a2 = __builtin_amdgcn_mfma_f32_16x16x32_bf16(ah, bl, a2, 0, 0, 0);
        a2 = __builtin_amdgcn_mfma_f32_16x16x32_bf16(al, bh, a2, 0, 0, 0);
        cur ^= 1;
    }

    const f32x4 acc = a1 + a2;

    if (last) {
        float* o = Yout + (size_t)(ti + wi * 16 + lq * 4) * M + tj + wj * 16 + lm;
        #pragma unroll
        for (int r = 0; r < 4; ++r) o[(size_t)r * M] = acc[r];
        return;
    }

    __syncthreads();
    float* Ct = (float*)sm;
    #pragma unroll
    for (int r = 0; r < 4; ++r)
        Ct[(wi * 16 + lq * 4 + r) * GSTR + (wj * 16 + lm)] = acc[r];
    __syncthreads();

    // Y hi/lo (row-major)
    {
        const int rr = t >> 3, cc = (t & 7) * 4;
        const float4 v4 = *(const float4*)(Ct + rr * GSTR + cc);
        const float v[4] = {v4.x, v4.y, v4.z, v4.w};
        unsigned short hi[4], lo[4];
        #pragma unroll
        for (int i = 0; i < 4; ++i) { hi[i] = f2bf(v[i]); lo[i] = f2bf(v[i] - bf2f(hi[i])); }
        *(uint2*)(Yhi + (size_t)(ti + rr) * M + tj + cc) = pack4(hi);
        *(uint2*)(Ylo + (size_t)(ti + rr) * M + tj + cc) = pack4(lo);
    }
    // Y^T hi/lo (transposed)
    {
        const int n = t >> 3, m0 = (t & 7) * 4;
        float u[4];
        #pragma unroll
        for (int i = 0; i < 4; ++i) u[i] = Ct[(m0 + i) * GSTR + n];
        unsigned short hi[4], lo[4];
        #pragma unroll
        for (int i = 0; i < 4; ++i) { hi[i] = f2bf(u[i]); lo[i] = f2bf(u[i] - bf2f(hi[i])); }
        *(uint2*)(YThi + (size_t)(tj + n) * D + ti + m0) = pack4(hi);
        *(uint2*)(YTlo + (size_t)(tj + n) * D + ti + m0) = pack4(lo);
    }
}

extern "C" void kernel_launch(void* const* d_in, const int* in_sizes, int n_in,
                              void* d_out, int out_size, void* d_ws, size_t ws_size,
                              hipStream_t stream) {
    const float* Xin = (const float*)d_in[0];
    float* out = (float*)d_out;
    char* w = (char*)d_ws;
    const size_t XB = (size_t)D * M * 2;  // 2 MB per bf16 D x M buffer

    unsigned short* Xhi[2] = {(unsigned short*)(w), (unsigned short*)(w + XB)};
    unsigned short* Xlo[2] = {(unsigned short*)(w + 2 * XB), (unsigned short*)(w + 3 * XB)};
    unsigned short* XThi = (unsigned short*)(w + 4 * XB);
    unsigned short* XTlo = (unsigned short*)(w + 5 * XB);
    unsigned short* Ahi = (unsigned short*)(w + 6 * XB);
    unsigned short* Alo = Ahi + (size_t)M * M;
    float* P = out;  // 4 splits x 1 MB = exactly d_out (4 MB); overwritten by last update

    init_split<<<D * M / 2048, 256, 0, stream>>>(Xin, Xhi[0], Xlo[0], XThi, XTlo);

    for (int it = 0; it < STEPS; ++it) {
        const int cur = it & 1, nxt = cur ^ 1;
        const int last = (it == STEPS - 1);
        gram_partial<<<dim3(M / 32, M / 32, GSPLIT), 256, 0, stream>>>(XThi, XTlo, P);
        reduce_a<<<M * M / 1024, 256, 0, stream>>>(P, Ahi, Alo);
        update_mfma<<<dim3(D / 32, M / 32), 256, 0, stream>>>(
            Xhi[cur], Xlo[cur], Ahi, Alo,
            Xhi[nxt], Xlo[nxt], XThi, XTlo, out, last);
    }
}